// Round 5
// baseline (2934.089 us; speedup 1.0000x reference)
//
#include <hip/hip_runtime.h>

// SimpleRNN: h_{t+1} = tanh(h Wh^T + x_t Wx^T + b), return h_1024.
// SEQ=1024, NB=64, HID=512, IN=512. W is [512][1024] = [Wh | Wx]. All fp32 I/O.
//
// Phase 1 (prepass): U[t][b][j] = x_t[b]·Wx[j] + b[j] as MFMA f16 GEMM, U f16 in ws.
// Phase 2 (recurrent): R5 REWRITE -- 64 WGs x 1024 threads, ONE WG PER BATCH.
//   The whole 512x512 Wh lives in the WG's registers (128 VGPRs/thread, 16 waves
//   x 64 lanes x 256 f16). The recurrence is now WG-local: no cross-WG publish,
//   no MALL store->poll round trip (was ~2400 of 3019 cy/step in R2; R4's rotated
//   poll made it worse -- clustered samples + compiler vmcnt drains). Per step:
//   1 barrier + 1024cy VALU-issue floor (512x512 MAC / 256 MAC/cy/CU).
//   h double-buffered in LDS (parity), 144B chunk stride (conflict-free b128:
//   banks (36c+4q)%32 distinct across the 8 chunks). DPP butterfly reduce
//   (quad_perm xor1/xor2 + row_half_mirror) -- all-VALU, kept from R4 (correct).
//   No hbuf, no memset, no cooperative launch.

#define SEQ 1024
#define NB  64
#define HID 512

typedef _Float16 half2v __attribute__((ext_vector_type(2)));
typedef _Float16 f16x8  __attribute__((ext_vector_type(8)));
typedef float    f32x4  __attribute__((ext_vector_type(4)));

#if __has_builtin(__builtin_amdgcn_fdot2)
#define DOT2(a, b, c) __builtin_amdgcn_fdot2((a), (b), (c), false)
#else
static __device__ __forceinline__ float DOT2(half2v a, half2v b, float c) {
  return c + (float)a.x * (float)b.x + (float)a.y * (float)b.y;
}
#endif

static __device__ __forceinline__ float fast_tanh(float x) {
  float e = __expf(2.0f * x);
  return (e - 1.0f) / (e + 1.0f);
}

// v += v permuted by DPP ctrl (ctrl must be a compile-time immediate)
template <int CTRL>
static __device__ __forceinline__ float dpp_add(float v) {
  int s = __builtin_bit_cast(int, v);
  int p = __builtin_amdgcn_update_dpp(0, s, CTRL, 0xF, 0xF, true);
  return v + __builtin_bit_cast(float, p);
}
#define DPP_QUAD_XOR1 0xB1  // quad_perm [1,0,3,2]
#define DPP_QUAD_XOR2 0x4E  // quad_perm [2,3,0,1]
#define DPP_HALF_MIRR 0x141 // row_half_mirror (lane ^= 7 within 8)

// ---------------------------------------------------------------- prepass ---
__global__ __launch_bounds__(256, 2)
void rnn_prepass(const float* __restrict__ X, const float* __restrict__ W,
                 const float* __restrict__ bias, _Float16* __restrict__ U) {
  __shared__ __align__(16) _Float16 As[128][40];  // +8 pad: bank-friendly
  __shared__ __align__(16) _Float16 Bs[128][40];
  const int tid = threadIdx.x;
  const int m0 = blockIdx.y * 128;   // 512 m-tiles (slow axis)
  const int n0 = blockIdx.x * 128;   // 4 n-tiles (fast axis: siblings co-run)
  const int wave = tid >> 6, lane = tid & 63;
  const int wm = (wave >> 1) * 64, wn = (wave & 1) * 64;  // 2x2 wave grid
  const int l15 = lane & 15, q = lane >> 4;

  f32x4 acc[4][4];
#pragma unroll
  for (int i = 0; i < 4; ++i)
#pragma unroll
    for (int j = 0; j < 4; ++j) acc[i][j] = (f32x4){0.f, 0.f, 0.f, 0.f};

  const int srow = tid >> 1;
  const int shalf = (tid & 1) * 16;

  for (int k0 = 0; k0 < 512; k0 += 32) {
    const float* asrc = X + (size_t)(m0 + srow) * 512 + k0 + shalf;
    const float* bsrc = W + (size_t)(n0 + srow) * 1024 + 512 + k0 + shalf;
    float4 a0 = *(const float4*)(asrc);
    float4 a1 = *(const float4*)(asrc + 4);
    float4 a2 = *(const float4*)(asrc + 8);
    float4 a3 = *(const float4*)(asrc + 12);
    float4 b0 = *(const float4*)(bsrc);
    float4 b1 = *(const float4*)(bsrc + 4);
    float4 b2 = *(const float4*)(bsrc + 8);
    float4 b3 = *(const float4*)(bsrc + 12);
    __syncthreads();  // previous iter's frag reads done before LDS overwrite
    f16x8 pa0 = {(_Float16)a0.x, (_Float16)a0.y, (_Float16)a0.z, (_Float16)a0.w,
                 (_Float16)a1.x, (_Float16)a1.y, (_Float16)a1.z, (_Float16)a1.w};
    f16x8 pa1 = {(_Float16)a2.x, (_Float16)a2.y, (_Float16)a2.z, (_Float16)a2.w,
                 (_Float16)a3.x, (_Float16)a3.y, (_Float16)a3.z, (_Float16)a3.w};
    f16x8 pb0 = {(_Float16)b0.x, (_Float16)b0.y, (_Float16)b0.z, (_Float16)b0.w,
                 (_Float16)b1.x, (_Float16)b1.y, (_Float16)b1.z, (_Float16)b1.w};
    f16x8 pb1 = {(_Float16)b2.x, (_Float16)b2.y, (_Float16)b2.z, (_Float16)b2.w,
                 (_Float16)b3.x, (_Float16)b3.y, (_Float16)b3.z, (_Float16)b3.w};
    *(f16x8*)&As[srow][shalf] = pa0;
    *(f16x8*)&As[srow][shalf + 8] = pa1;
    *(f16x8*)&Bs[srow][shalf] = pb0;
    *(f16x8*)&Bs[srow][shalf + 8] = pb1;
    __syncthreads();
    f16x8 av[4], bv[4];
#pragma unroll
    for (int i = 0; i < 4; ++i)
      av[i] = *(const f16x8*)&As[wm + i * 16 + l15][q * 8];
#pragma unroll
    for (int j = 0; j < 4; ++j)
      bv[j] = *(const f16x8*)&Bs[wn + j * 16 + l15][q * 8];
#pragma unroll
    for (int i = 0; i < 4; ++i)
#pragma unroll
      for (int j = 0; j < 4; ++j)
        acc[i][j] = __builtin_amdgcn_mfma_f32_16x16x32_f16(av[i], bv[j], acc[i][j], 0, 0, 0);
  }
  float bj[4];
#pragma unroll
  for (int j = 0; j < 4; ++j) bj[j] = bias[n0 + wn + j * 16 + l15];
#pragma unroll
  for (int i = 0; i < 4; ++i)
#pragma unroll
    for (int j = 0; j < 4; ++j)
#pragma unroll
      for (int r = 0; r < 4; ++r) {
        // C/D layout: col = lane&15, row = (lane>>4)*4 + reg  [m89/m91]
        int m = m0 + wm + i * 16 + q * 4 + r;
        int n = n0 + wn + j * 16 + l15;
        U[(size_t)m * 512 + n] = (_Float16)(acc[i][j][r] + bj[j]);
      }
}

// -------------------------------------------------------------- recurrent ---
// 64 WGs x 1024 threads; WG = one batch. 16 waves: wave wvi, lane l.
// Thread owns rows 4*rg..4*rg+3 (rg = wvi*8 + (l>>3), 0..127) x cols 64c..64c+63.
__global__ __launch_bounds__(1024, 4)
void rnn_recur(const float* __restrict__ W, const _Float16* __restrict__ U,
               float* __restrict__ out) {
  const int batch = blockIdx.x;
  const int tid = threadIdx.x;
  const int wvi = tid >> 6;      // wave 0..15
  const int l   = tid & 63;
  const int jj  = l >> 3;        // row group within wave
  const int c   = l & 7;         // k-chunk 0..7 (64 ks each)
  const int rg  = wvi * 8 + jj;  // row group 0..127

  // h double-buffer: 8 chunks of 64 f16, chunk stride 144 B.
  // Read banks (36c+4q)%32 distinct across the 8 chunks -> conflict-free b128.
  __shared__ __align__(16) unsigned char hmem[2][8 * 144];

  // ---- one-time: Wh rows 4rg..4rg+3, cols 64c..64c+63 -> 32 x f16x8 (128 regs)
  f16x8 wreg[32];
#pragma unroll
  for (int i = 0; i < 4; ++i) {
    const float* wrow = W + (size_t)(4 * rg + i) * 1024 + 64 * c;
#pragma unroll
    for (int q = 0; q < 8; ++q) {
      float4 wa = *(const float4*)(wrow + 8 * q);
      float4 wb = *(const float4*)(wrow + 8 * q + 4);
      f16x8 p = {(_Float16)wa.x, (_Float16)wa.y, (_Float16)wa.z, (_Float16)wa.w,
                 (_Float16)wb.x, (_Float16)wb.y, (_Float16)wb.z, (_Float16)wb.w};
      wreg[i * 8 + q] = p;
    }
  }

  // h_0 = 0
  if (tid < 256)
    *(unsigned int*)(hmem[0] + (tid >> 5) * 144 + (tid & 31) * 4) = 0u;
  __syncthreads();

  const unsigned int* ubase = (const unsigned int*)U;
  const bool puber = (c < 2);         // 256 publisher threads
  const int wpub = 2 * rg + c;        // h word 0..255 (2 f16 each)

  float h0f = 0.f, h1f = 0.f;
  for (int t = 0; t < SEQ; ++t) {
    // U word for this step (issued early; used ~1000cy later -> HBM lat hidden)
    unsigned int ubits = 0;
    if (puber)
      ubits = ubase[((size_t)t * NB + batch) * 256 + wpub];

    // 4 rows x 64 ks from reg-resident weights: 8 ds_read_b128 + 128 v_dot2
    float a[4] = {0.f, 0.f, 0.f, 0.f};
    const unsigned char* hc = hmem[t & 1] + c * 144;
#pragma unroll
    for (int q = 0; q < 8; ++q) {
      f16x8 hv = *(const f16x8*)(hc + 16 * q);
      half2v h0 = {hv[0], hv[1]}, h1 = {hv[2], hv[3]},
             h2 = {hv[4], hv[5]}, h3 = {hv[6], hv[7]};
#pragma unroll
      for (int i = 0; i < 4; ++i) {
        f16x8 wv = wreg[i * 8 + q];
        half2v w0 = {wv[0], wv[1]}, w1 = {wv[2], wv[3]},
               w2 = {wv[4], wv[5]}, w3 = {wv[6], wv[7]};
        a[i] = DOT2(w0, h0, a[i]);
        a[i] = DOT2(w1, h1, a[i]);
        a[i] = DOT2(w2, h2, a[i]);
        a[i] = DOT2(w3, h3, a[i]);
      }
    }
    // all-VALU butterfly over the 8 k-chunks (lane bits 0..2)
#pragma unroll
    for (int i = 0; i < 4; ++i) a[i] = dpp_add<DPP_QUAD_XOR1>(a[i]);
#pragma unroll
    for (int i = 0; i < 4; ++i) a[i] = dpp_add<DPP_QUAD_XOR2>(a[i]);
#pragma unroll
    for (int i = 0; i < 4; ++i) a[i] = dpp_add<DPP_HALF_MIRR>(a[i]);

    // h_{t+1}: tanh + write straight into the other LDS parity buffer.
    if (puber) {
      half2v uh = __builtin_bit_cast(half2v, ubits);
      float s0 = (c == 0) ? a[0] : a[2];
      float s1 = (c == 0) ? a[1] : a[3];
      h0f = fast_tanh(s0 + (float)uh.x);
      h1f = fast_tanh(s1 + (float)uh.y);
      half2v hh;
      hh.x = (_Float16)h0f;
      hh.y = (_Float16)h1f;
      *(unsigned int*)(hmem[(t + 1) & 1] + (wpub >> 5) * 144 + (wpub & 31) * 4) =
          __builtin_bit_cast(unsigned int, hh);
    }
    // ONE barrier/step: writes to hmem[(t+1)&1] above happen-before step t+1's
    // reads; buffer t&1 is next overwritten at step t+1's tail, i.e. after this
    // barrier, by which time all step-t reads of it are done.
    __syncthreads();
  }
  if (puber) {
    out[(size_t)batch * HID + 2 * wpub]     = h0f;
    out[(size_t)batch * HID + 2 * wpub + 1] = h1f;
  }
}

// ------------------------------------------------------------------- host ---
extern "C" void kernel_launch(void* const* d_in, const int* in_sizes, int n_in,
                              void* d_out, int out_size, void* d_ws, size_t ws_size,
                              hipStream_t stream) {
  const float* X    = (const float*)d_in[0];  // [1024][64][512]
  const float* W    = (const float*)d_in[1];  // [512][1024]
  const float* bias = (const float*)d_in[2];  // [512]
  float* out = (float*)d_out;                 // [64][512]

  // ws layout: U f16 (64 MiB)
  _Float16* U = (_Float16*)d_ws;

  rnn_prepass<<<dim3(4, 512), dim3(256), 0, stream>>>(X, W, bias, U);
  rnn_recur<<<dim3(64), dim3(1024), 0, stream>>>(W, U, out);
}

// Round 6
// 2776.632 us; speedup vs baseline: 1.0567x; 1.0567x over previous
//
#include <hip/hip_runtime.h>

// SimpleRNN: h_{t+1} = tanh(h Wh^T + x_t Wx^T + b), return h_1024.
// SEQ=1024, NB=64, HID=512, IN=512. W is [512][1024] = [Wh | Wx]. All fp32 I/O.
//
// Phase 1 (prepass): U[t][b][j] = x_t[b]·Wx[j] + b[j] as MFMA f16 GEMM, U f16 in ws.
// Phase 2 (recurrent): R6 -- 64 WGs x 256 THREADS, one batch per WG, WG-local
//   recurrence (no cross-WG sync at all). R5's 1024-thread version spilled:
//   4 waves/SIMD caps each wave at 128 regs (pool = 512/wave-slot; m69), so the
//   128-reg wreg went to scratch -> 512 KB/CU/step L2 restream (~5000 cy/step,
//   invisible in FETCH since TCC counts HBM only). At 256 threads = 1 wave/SIMD
//   the cap is 512 regs: HYBRID weight residency fits --
//     rows i%16 in 0..11  -> registers: wreg[96] f16x8 = 384 regs/thread
//     rows i%16 in 12..15 -> LDS: wlds[32][256] f16x8 = 128 KB, thread-order
//       layout (lane-consecutive 16B -> conflict-free, proven 0-conflict in R0)
//   Per thread: rows rgrp*16..+15 (rgrp=tid>>3) x ks 64c..64c+63 (c=tid&7).
//   Step = 512 dot2 + 32 LDS w-reads + DPP butterfly (c in lane bits 0..2) +
//   tanh + 1 barrier ~= 1250 cy issue-bound; was 3019 cy sync-bound (R2) and
//   6400 cy spill-bound (R5). Reg budget 384+~55 < 450 no-spill line (m08).

#define SEQ 1024
#define NB  64
#define HID 512

typedef _Float16 half2v __attribute__((ext_vector_type(2)));
typedef _Float16 f16x8  __attribute__((ext_vector_type(8)));
typedef float    f32x4  __attribute__((ext_vector_type(4)));

#if __has_builtin(__builtin_amdgcn_fdot2)
#define DOT2(a, b, c) __builtin_amdgcn_fdot2((a), (b), (c), false)
#else
static __device__ __forceinline__ float DOT2(half2v a, half2v b, float c) {
  return c + (float)a.x * (float)b.x + (float)a.y * (float)b.y;
}
#endif

static __device__ __forceinline__ float fast_tanh(float x) {
  float e = __expf(2.0f * x);
  return (e - 1.0f) / (e + 1.0f);
}

// v += v permuted by DPP ctrl (ctrl must be a compile-time immediate)
template <int CTRL>
static __device__ __forceinline__ float dpp_add(float v) {
  int s = __builtin_bit_cast(int, v);
  int p = __builtin_amdgcn_update_dpp(0, s, CTRL, 0xF, 0xF, true);
  return v + __builtin_bit_cast(float, p);
}
#define DPP_QUAD_XOR1 0xB1  // quad_perm [1,0,3,2]
#define DPP_QUAD_XOR2 0x4E  // quad_perm [2,3,0,1]
#define DPP_HALF_MIRR 0x141 // row_half_mirror (lane ^= 7 within 8)

// ---------------------------------------------------------------- prepass ---
__global__ __launch_bounds__(256, 2)
void rnn_prepass(const float* __restrict__ X, const float* __restrict__ W,
                 const float* __restrict__ bias, _Float16* __restrict__ U) {
  __shared__ __align__(16) _Float16 As[128][40];  // +8 pad: bank-friendly
  __shared__ __align__(16) _Float16 Bs[128][40];
  const int tid = threadIdx.x;
  const int m0 = blockIdx.y * 128;   // 512 m-tiles (slow axis)
  const int n0 = blockIdx.x * 128;   // 4 n-tiles (fast axis: siblings co-run)
  const int wave = tid >> 6, lane = tid & 63;
  const int wm = (wave >> 1) * 64, wn = (wave & 1) * 64;  // 2x2 wave grid
  const int l15 = lane & 15, q = lane >> 4;

  f32x4 acc[4][4];
#pragma unroll
  for (int i = 0; i < 4; ++i)
#pragma unroll
    for (int j = 0; j < 4; ++j) acc[i][j] = (f32x4){0.f, 0.f, 0.f, 0.f};

  const int srow = tid >> 1;
  const int shalf = (tid & 1) * 16;

  for (int k0 = 0; k0 < 512; k0 += 32) {
    const float* asrc = X + (size_t)(m0 + srow) * 512 + k0 + shalf;
    const float* bsrc = W + (size_t)(n0 + srow) * 1024 + 512 + k0 + shalf;
    float4 a0 = *(const float4*)(asrc);
    float4 a1 = *(const float4*)(asrc + 4);
    float4 a2 = *(const float4*)(asrc + 8);
    float4 a3 = *(const float4*)(asrc + 12);
    float4 b0 = *(const float4*)(bsrc);
    float4 b1 = *(const float4*)(bsrc + 4);
    float4 b2 = *(const float4*)(bsrc + 8);
    float4 b3 = *(const float4*)(bsrc + 12);
    __syncthreads();  // previous iter's frag reads done before LDS overwrite
    f16x8 pa0 = {(_Float16)a0.x, (_Float16)a0.y, (_Float16)a0.z, (_Float16)a0.w,
                 (_Float16)a1.x, (_Float16)a1.y, (_Float16)a1.z, (_Float16)a1.w};
    f16x8 pa1 = {(_Float16)a2.x, (_Float16)a2.y, (_Float16)a2.z, (_Float16)a2.w,
                 (_Float16)a3.x, (_Float16)a3.y, (_Float16)a3.z, (_Float16)a3.w};
    f16x8 pb0 = {(_Float16)b0.x, (_Float16)b0.y, (_Float16)b0.z, (_Float16)b0.w,
                 (_Float16)b1.x, (_Float16)b1.y, (_Float16)b1.z, (_Float16)b1.w};
    f16x8 pb1 = {(_Float16)b2.x, (_Float16)b2.y, (_Float16)b2.z, (_Float16)b2.w,
                 (_Float16)b3.x, (_Float16)b3.y, (_Float16)b3.z, (_Float16)b3.w};
    *(f16x8*)&As[srow][shalf] = pa0;
    *(f16x8*)&As[srow][shalf + 8] = pa1;
    *(f16x8*)&Bs[srow][shalf] = pb0;
    *(f16x8*)&Bs[srow][shalf + 8] = pb1;
    __syncthreads();
    f16x8 av[4], bv[4];
#pragma unroll
    for (int i = 0; i < 4; ++i)
      av[i] = *(const f16x8*)&As[wm + i * 16 + l15][q * 8];
#pragma unroll
    for (int j = 0; j < 4; ++j)
      bv[j] = *(const f16x8*)&Bs[wn + j * 16 + l15][q * 8];
#pragma unroll
    for (int i = 0; i < 4; ++i)
#pragma unroll
      for (int j = 0; j < 4; ++j)
        acc[i][j] = __builtin_amdgcn_mfma_f32_16x16x32_f16(av[i], bv[j], acc[i][j], 0, 0, 0);
  }
  float bj[4];
#pragma unroll
  for (int j = 0; j < 4; ++j) bj[j] = bias[n0 + wn + j * 16 + l15];
#pragma unroll
  for (int i = 0; i < 4; ++i)
#pragma unroll
    for (int j = 0; j < 4; ++j)
#pragma unroll
      for (int r = 0; r < 4; ++r) {
        // C/D layout: col = lane&15, row = (lane>>4)*4 + reg  [m89/m91]
        int m = m0 + wm + i * 16 + q * 4 + r;
        int n = n0 + wn + j * 16 + l15;
        U[(size_t)m * 512 + n] = (_Float16)(acc[i][j][r] + bj[j]);
      }
}

// -------------------------------------------------------------- recurrent ---
// 64 WGs x 256 threads; WG = one batch. Thread (rgrp=tid>>3, c=tid&7) owns
// rows rgrp*16..rgrp*16+15, k-chunk 64c..64c+63. Rows %16 in 0..11 from regs,
// 12..15 from LDS.
__global__ __launch_bounds__(256, 1)
void rnn_recur(const float* __restrict__ W, const _Float16* __restrict__ U,
               float* __restrict__ out) {
  const int batch = blockIdx.x;
  const int tid = threadIdx.x;
  const int c    = tid & 7;       // k-chunk 0..7 (64 ks)
  const int rgrp = tid >> 3;      // 0..31, rows rgrp*16..+15

  // LDS weights (rows %16 = 12..15): thread-order chunks, lane-consecutive 16B
  __shared__ __align__(16) f16x8 wlds[32][256];          // 128 KB
  // h double-buffer: 8 chunks of 64 f16, chunk stride 144 B (conflict-free)
  __shared__ __align__(16) unsigned char hmem[2][8 * 144];

  // ---- one-time weight load: 12 reg-rows + 4 LDS-rows per (rgrp,c)
  f16x8 wreg[96];  // 384 VGPR/AGPR
#pragma unroll
  for (int i = 0; i < 12; ++i) {
    const float* wrow = W + (size_t)(rgrp * 16 + i) * 1024 + 64 * c;
#pragma unroll
    for (int q = 0; q < 8; ++q) {
      float4 wa = *(const float4*)(wrow + 8 * q);
      float4 wb = *(const float4*)(wrow + 8 * q + 4);
      f16x8 p = {(_Float16)wa.x, (_Float16)wa.y, (_Float16)wa.z, (_Float16)wa.w,
                 (_Float16)wb.x, (_Float16)wb.y, (_Float16)wb.z, (_Float16)wb.w};
      wreg[i * 8 + q] = p;
    }
  }
#pragma unroll
  for (int j = 0; j < 4; ++j) {
    const float* wrow = W + (size_t)(rgrp * 16 + 12 + j) * 1024 + 64 * c;
#pragma unroll
    for (int q = 0; q < 8; ++q) {
      float4 wa = *(const float4*)(wrow + 8 * q);
      float4 wb = *(const float4*)(wrow + 8 * q + 4);
      f16x8 p = {(_Float16)wa.x, (_Float16)wa.y, (_Float16)wa.z, (_Float16)wa.w,
                 (_Float16)wb.x, (_Float16)wb.y, (_Float16)wb.z, (_Float16)wb.w};
      wlds[j * 8 + q][tid] = p;
    }
  }

  // h_0 = 0 (each thread zeroes word tid)
  *(unsigned int*)(hmem[0] + (tid >> 5) * 144 + (tid & 31) * 4) = 0u;
  __syncthreads();

  const unsigned int* ubase = (const unsigned int*)U;

  float h0f = 0.f, h1f = 0.f;
  for (int t = 0; t < SEQ; ++t) {
    // U word for rows {2*tid, 2*tid+1} (issued early; used ~1200cy later)
    unsigned int ubits = ubase[((size_t)t * NB + batch) * 256 + tid];

    // 16 rows x 64 ks: 12 rows from regs, 4 from LDS
    float a[16];
#pragma unroll
    for (int i = 0; i < 16; ++i) a[i] = 0.f;
    const unsigned char* hc = hmem[t & 1] + c * 144;
#pragma unroll
    for (int q = 0; q < 8; ++q) {
      f16x8 hv = *(const f16x8*)(hc + 16 * q);
      half2v h0 = {hv[0], hv[1]}, h1 = {hv[2], hv[3]},
             h2 = {hv[4], hv[5]}, h3 = {hv[6], hv[7]};
#pragma unroll
      for (int i = 0; i < 12; ++i) {
        f16x8 wv = wreg[i * 8 + q];
        half2v w0 = {wv[0], wv[1]}, w1 = {wv[2], wv[3]},
               w2 = {wv[4], wv[5]}, w3 = {wv[6], wv[7]};
        a[i] = DOT2(w0, h0, a[i]);
        a[i] = DOT2(w1, h1, a[i]);
        a[i] = DOT2(w2, h2, a[i]);
        a[i] = DOT2(w3, h3, a[i]);
      }
#pragma unroll
      for (int j = 0; j < 4; ++j) {
        f16x8 wv = wlds[j * 8 + q][tid];
        half2v w0 = {wv[0], wv[1]}, w1 = {wv[2], wv[3]},
               w2 = {wv[4], wv[5]}, w3 = {wv[6], wv[7]};
        a[12 + j] = DOT2(w0, h0, a[12 + j]);
        a[12 + j] = DOT2(w1, h1, a[12 + j]);
        a[12 + j] = DOT2(w2, h2, a[12 + j]);
        a[12 + j] = DOT2(w3, h3, a[12 + j]);
      }
    }
    // all-VALU butterfly over the 8 k-chunks (lane bits 0..2)
#pragma unroll
    for (int i = 0; i < 16; ++i) a[i] = dpp_add<DPP_QUAD_XOR1>(a[i]);
#pragma unroll
    for (int i = 0; i < 16; ++i) a[i] = dpp_add<DPP_QUAD_XOR2>(a[i]);
#pragma unroll
    for (int i = 0; i < 16; ++i) a[i] = dpp_add<DPP_HALF_MIRR>(a[i]);

    // lane c of each 8-lane group takes rows {16rgrp+2c, +1} = {2tid, 2tid+1}
    // (static-index select chain -- no runtime reg indexing, rule #20)
    float s0 = a[0], s1 = a[1];
#pragma unroll
    for (int k = 1; k < 8; ++k) {
      if (c == k) { s0 = a[2 * k]; s1 = a[2 * k + 1]; }
    }
    half2v uh = __builtin_bit_cast(half2v, ubits);
    h0f = fast_tanh(s0 + (float)uh.x);
    h1f = fast_tanh(s1 + (float)uh.y);
    half2v hh;
    hh.x = (_Float16)h0f;
    hh.y = (_Float16)h1f;
    *(unsigned int*)(hmem[(t + 1) & 1] + (tid >> 5) * 144 + (tid & 31) * 4) =
        __builtin_bit_cast(unsigned int, hh);
    // ONE barrier/step: h_{t+1} writes (other parity) happen-before step t+1
    // reads; buffer t&1 is only rewritten at step t+1's tail (after this
    // barrier), by which time all step-t reads of it are done.
    __syncthreads();
  }
  out[(size_t)batch * HID + 2 * tid]     = h0f;
  out[(size_t)batch * HID + 2 * tid + 1] = h1f;
}

// ------------------------------------------------------------------- host ---
extern "C" void kernel_launch(void* const* d_in, const int* in_sizes, int n_in,
                              void* d_out, int out_size, void* d_ws, size_t ws_size,
                              hipStream_t stream) {
  const float* X    = (const float*)d_in[0];  // [1024][64][512]
  const float* W    = (const float*)d_in[1];  // [512][1024]
  const float* bias = (const float*)d_in[2];  // [512]
  float* out = (float*)d_out;                 // [64][512]

  // ws layout: U f16 (64 MiB)
  _Float16* U = (_Float16*)d_ws;

  rnn_prepass<<<dim3(4, 512), dim3(256), 0, stream>>>(X, W, bias, U);
  rnn_recur<<<dim3(64), dim3(256), 0, stream>>>(W, U, out);
}

// Round 7
// 1278.647 us; speedup vs baseline: 2.2947x; 2.1715x over previous
//
#include <hip/hip_runtime.h>

// SimpleRNN: h_{t+1} = tanh(h Wh^T + x_t Wx^T + b), return h_1024.
// SEQ=1024, NB=64, HID=512, IN=512. W is [512][1024] = [Wh | Wx]. All fp32 I/O.
//
// Phase 1 (prepass): U[t][b][j] = x_t[b]·Wx[j] + b[j] as MFMA f16 GEMM, U f16 in ws.
// Phase 2 (recurrent): R7 = R2's verified distributed structure (256 WGs =
//   64 batches x 4 row-slices, 1 WG/CU, Wh slice in 128 regs/thread) plus the
//   three R4 components that were correct but masked by the rotated-poll
//   regression (rotated poll clustered samples + compiler vmcnt drains):
//   (a) simple 1-deep poll (R2's verified 1288us behavior),
//   (b) DPP butterfly reduce (all-VALU; HW-verified in R4/R6),
//   (c) hmem double-buffer -> ONE barrier/step (2-deep parity safe),
//   (d) NEW: publishers write own-slice words straight to hmem[(t+1)&1];
//       own-slice threads skip polling (disjoint words, barrier-ordered).
//   R5/R6 lesson: concentrating a batch on one CU can't work -- VALU can only
//   address v0..v255, so >200 weight regs/thread spill; 512KB/step through one
//   CU's RF/LDS floors at ~2x R2's step. Distributed + sync is the skeleton.

#define SEQ 1024
#define NB  64
#define HID 512

typedef _Float16 half2v __attribute__((ext_vector_type(2)));
typedef _Float16 f16x8  __attribute__((ext_vector_type(8)));
typedef float    f32x4  __attribute__((ext_vector_type(4)));

#if __has_builtin(__builtin_amdgcn_fdot2)
#define DOT2(a, b, c) __builtin_amdgcn_fdot2((a), (b), (c), false)
#else
static __device__ __forceinline__ float DOT2(half2v a, half2v b, float c) {
  return c + (float)a.x * (float)b.x + (float)a.y * (float)b.y;
}
#endif

static __device__ __forceinline__ float fast_tanh(float x) {
  float e = __expf(2.0f * x);
  return (e - 1.0f) / (e + 1.0f);
}

// v += v permuted by DPP ctrl (ctrl must be a compile-time immediate)
template <int CTRL>
static __device__ __forceinline__ float dpp_add(float v) {
  int s = __builtin_bit_cast(int, v);
  int p = __builtin_amdgcn_update_dpp(0, s, CTRL, 0xF, 0xF, true);
  return v + __builtin_bit_cast(float, p);
}
#define DPP_QUAD_XOR1 0xB1  // quad_perm [1,0,3,2]
#define DPP_QUAD_XOR2 0x4E  // quad_perm [2,3,0,1]
#define DPP_HALF_MIRR 0x141 // row_half_mirror (lane ^= 7 within 8)

// ---------------------------------------------------------------- prepass ---
__global__ __launch_bounds__(256, 2)
void rnn_prepass(const float* __restrict__ X, const float* __restrict__ W,
                 const float* __restrict__ bias, _Float16* __restrict__ U) {
  __shared__ __align__(16) _Float16 As[128][40];  // +8 pad: bank-friendly
  __shared__ __align__(16) _Float16 Bs[128][40];
  const int tid = threadIdx.x;
  const int m0 = blockIdx.y * 128;   // 512 m-tiles (slow axis)
  const int n0 = blockIdx.x * 128;   // 4 n-tiles (fast axis)
  const int wave = tid >> 6, lane = tid & 63;
  const int wm = (wave >> 1) * 64, wn = (wave & 1) * 64;  // 2x2 wave grid
  const int l15 = lane & 15, q = lane >> 4;

  f32x4 acc[4][4];
#pragma unroll
  for (int i = 0; i < 4; ++i)
#pragma unroll
    for (int j = 0; j < 4; ++j) acc[i][j] = (f32x4){0.f, 0.f, 0.f, 0.f};

  const int srow = tid >> 1;
  const int shalf = (tid & 1) * 16;

  for (int k0 = 0; k0 < 512; k0 += 32) {
    const float* asrc = X + (size_t)(m0 + srow) * 512 + k0 + shalf;
    const float* bsrc = W + (size_t)(n0 + srow) * 1024 + 512 + k0 + shalf;
    float4 a0 = *(const float4*)(asrc);
    float4 a1 = *(const float4*)(asrc + 4);
    float4 a2 = *(const float4*)(asrc + 8);
    float4 a3 = *(const float4*)(asrc + 12);
    float4 b0 = *(const float4*)(bsrc);
    float4 b1 = *(const float4*)(bsrc + 4);
    float4 b2 = *(const float4*)(bsrc + 8);
    float4 b3 = *(const float4*)(bsrc + 12);
    __syncthreads();  // previous iter's frag reads done before LDS overwrite
    f16x8 pa0 = {(_Float16)a0.x, (_Float16)a0.y, (_Float16)a0.z, (_Float16)a0.w,
                 (_Float16)a1.x, (_Float16)a1.y, (_Float16)a1.z, (_Float16)a1.w};
    f16x8 pa1 = {(_Float16)a2.x, (_Float16)a2.y, (_Float16)a2.z, (_Float16)a2.w,
                 (_Float16)a3.x, (_Float16)a3.y, (_Float16)a3.z, (_Float16)a3.w};
    f16x8 pb0 = {(_Float16)b0.x, (_Float16)b0.y, (_Float16)b0.z, (_Float16)b0.w,
                 (_Float16)b1.x, (_Float16)b1.y, (_Float16)b1.z, (_Float16)b1.w};
    f16x8 pb1 = {(_Float16)b2.x, (_Float16)b2.y, (_Float16)b2.z, (_Float16)b2.w,
                 (_Float16)b3.x, (_Float16)b3.y, (_Float16)b3.z, (_Float16)b3.w};
    *(f16x8*)&As[srow][shalf] = pa0;
    *(f16x8*)&As[srow][shalf + 8] = pa1;
    *(f16x8*)&Bs[srow][shalf] = pb0;
    *(f16x8*)&Bs[srow][shalf + 8] = pb1;
    __syncthreads();
    f16x8 av[4], bv[4];
#pragma unroll
    for (int i = 0; i < 4; ++i)
      av[i] = *(const f16x8*)&As[wm + i * 16 + l15][q * 8];
#pragma unroll
    for (int j = 0; j < 4; ++j)
      bv[j] = *(const f16x8*)&Bs[wn + j * 16 + l15][q * 8];
#pragma unroll
    for (int i = 0; i < 4; ++i)
#pragma unroll
      for (int j = 0; j < 4; ++j)
        acc[i][j] = __builtin_amdgcn_mfma_f32_16x16x32_f16(av[i], bv[j], acc[i][j], 0, 0, 0);
  }
  float bj[4];
#pragma unroll
  for (int j = 0; j < 4; ++j) bj[j] = bias[n0 + wn + j * 16 + l15];
#pragma unroll
  for (int i = 0; i < 4; ++i)
#pragma unroll
    for (int j = 0; j < 4; ++j)
#pragma unroll
      for (int r = 0; r < 4; ++r) {
        // C/D layout: col = lane&15, row = (lane>>4)*4 + reg  [m89/m91]
        int m = m0 + wm + i * 16 + q * 4 + r;
        int n = n0 + wn + j * 16 + l15;
        U[(size_t)m * 512 + n] = (_Float16)(acc[i][j][r] + bj[j]);
      }
}

// -------------------------------------------------------------- recurrent ---
__global__ __launch_bounds__(256, 1)
void rnn_recur(const float* __restrict__ W, const _Float16* __restrict__ U,
               unsigned long long* hbuf, float* __restrict__ out) {
  const int blk = blockIdx.x;
  const int batch = blk & 63;
  const int g = blk >> 6;      // row-slice 0..3 (rows 128g..128g+127)
  const int tid = threadIdx.x;
  const int wvi = tid >> 6;    // wave 0..3
  const int l   = tid & 63;
  const int jj  = l >> 3;      // row group within wave (4 rows each)
  const int c   = l & 7;       // k-chunk 0..7 (64 k's each)
  const int rg  = wvi * 8 + jj;  // WG row group 0..31

  // double-buffered h staging: 8 chunks of 64 f16, chunk stride 144 B
  // (reads at c*144+16q tile all 32 banks across the 8 distinct c).
  __shared__ __align__(16) unsigned char hmem[2][8 * 144];

  // ---- one-time: Wh rows 128g+4rg..+3, cols 64c..64c+63 -> 32 x f16x8 (128 regs)
  f16x8 wreg[32];
#pragma unroll
  for (int i = 0; i < 4; ++i) {
    const float* wrow = W + (size_t)(128 * g + 4 * rg + i) * 1024 + 64 * c;
#pragma unroll
    for (int q = 0; q < 8; ++q) {
      float4 wa = *(const float4*)(wrow + 8 * q);
      float4 wb = *(const float4*)(wrow + 8 * q + 4);
      f16x8 p = {(_Float16)wa.x, (_Float16)wa.y, (_Float16)wa.z, (_Float16)wa.w,
                 (_Float16)wb.x, (_Float16)wb.y, (_Float16)wb.z, (_Float16)wb.w};
      wreg[i * 8 + q] = p;
    }
  }

  // h_0 = 0 staged locally (t=0's barrier orders this before first reads)
  *(unsigned int*)(hmem[0] + (tid >> 5) * 144 + (tid & 31) * 4) = 0u;

  const unsigned int* ubase = (const unsigned int*)U;
  unsigned long long* hb = hbuf + (size_t)batch * 256;  // parity stride NB*256

  const bool puber = (c < 2);
  const int wpub = 2 * rg + c;        // word within WG slice (publishers)
  const int wid  = g * 64 + wpub;     // global word 0..255
  // own-slice words arrive via the publisher LDS shortcut -> no poll for them
  const bool ownword = (tid >= g * 64) && (tid < g * 64 + 64);

  float h0f = 0.f, h1f = 0.f;
  for (int t = 0; t < SEQ; ++t) {
    // prefetch this step's U word (publishers; independent of sync)
    unsigned int ubits = 0;
    if (puber)
      ubits = ubase[((size_t)t * NB + batch) * 256 + wid];

    // poll REMOTE words only (simple 1-deep poll -- R2's verified behavior)
    if (!ownword) {
      const unsigned long long* src = hb + (size_t)(t & 1) * (NB * 256) + tid;
      unsigned long long e;
      do {
        e = __hip_atomic_load(src, __ATOMIC_RELAXED, __HIP_MEMORY_SCOPE_AGENT);
      } while ((unsigned int)(e >> 32) != (unsigned int)t);
      *(unsigned int*)(hmem[t & 1] + (tid >> 5) * 144 + (tid & 31) * 4) =
          (unsigned int)e;
    }
    __syncthreads();  // the ONE barrier per step (hmem double-buffered)

    // 4 rows x 64 ks from reg-resident weights: 8 ds_read_b128 + 128 v_dot2
    float a[4] = {0.f, 0.f, 0.f, 0.f};
    const unsigned char* hc = hmem[t & 1] + c * 144;
#pragma unroll
    for (int q = 0; q < 8; ++q) {
      f16x8 hv = *(const f16x8*)(hc + 16 * q);
      half2v h0 = {hv[0], hv[1]}, h1 = {hv[2], hv[3]},
             h2 = {hv[4], hv[5]}, h3 = {hv[6], hv[7]};
#pragma unroll
      for (int i = 0; i < 4; ++i) {
        f16x8 wv = wreg[i * 8 + q];
        half2v w0 = {wv[0], wv[1]}, w1 = {wv[2], wv[3]},
               w2 = {wv[4], wv[5]}, w3 = {wv[6], wv[7]};
        a[i] = DOT2(w0, h0, a[i]);
        a[i] = DOT2(w1, h1, a[i]);
        a[i] = DOT2(w2, h2, a[i]);
        a[i] = DOT2(w3, h3, a[i]);
      }
    }
    // all-VALU butterfly over the 8 k-chunks (lane bits 0..2)
#pragma unroll
    for (int i = 0; i < 4; ++i) a[i] = dpp_add<DPP_QUAD_XOR1>(a[i]);
#pragma unroll
    for (int i = 0; i < 4; ++i) a[i] = dpp_add<DPP_QUAD_XOR2>(a[i]);
#pragma unroll
    for (int i = 0; i < 4; ++i) a[i] = dpp_add<DPP_HALF_MIRR>(a[i]);

    // publish: follows the barrier(t) => all remote slices reached tag t =>
    // every remote WG finished reading tag t-1 from this parity slot. The
    // hmem[(t+1)&1] shortcut write is disjoint from poller writes (own-slice
    // words vs remote words) and ordered by barrier(t+1) before its readers.
    if (puber) {
      half2v uh = __builtin_bit_cast(half2v, ubits);
      float s0 = (c == 0) ? a[0] : a[2];
      float s1 = (c == 0) ? a[1] : a[3];
      h0f = fast_tanh(s0 + (float)uh.x);
      h1f = fast_tanh(s1 + (float)uh.y);
      half2v hh;
      hh.x = (_Float16)h0f;
      hh.y = (_Float16)h1f;
      unsigned int hbits = __builtin_bit_cast(unsigned int, hh);
      unsigned long long word =
          ((unsigned long long)(unsigned int)(t + 1) << 32) |
          (unsigned long long)hbits;
      __hip_atomic_store(hb + (size_t)((t + 1) & 1) * (NB * 256) + wid, word,
                         __ATOMIC_RELAXED, __HIP_MEMORY_SCOPE_AGENT);
      *(unsigned int*)(hmem[(t + 1) & 1] + (wid >> 5) * 144 + (wid & 31) * 4) =
          hbits;
    }
    // no second barrier: step t+1 stages into hmem[(t+1)&1]; hmem[t&1] is next
    // written by step t+1's publishers (after barrier(t+1)), by which time all
    // step-t reads of it are done.
  }
  if (puber) {
    out[(size_t)batch * HID + 128 * g + 2 * wpub]     = h0f;
    out[(size_t)batch * HID + 128 * g + 2 * wpub + 1] = h1f;
  }
}

// ------------------------------------------------------------------- host ---
extern "C" void kernel_launch(void* const* d_in, const int* in_sizes, int n_in,
                              void* d_out, int out_size, void* d_ws, size_t ws_size,
                              hipStream_t stream) {
  const float* X    = (const float*)d_in[0];  // [1024][64][512]
  const float* W    = (const float*)d_in[1];  // [512][1024]
  const float* bias = (const float*)d_in[2];  // [512]
  float* out = (float*)d_out;                 // [64][512]

  // ws layout: U f16 (64 MiB) | hbuf u64[2][64][256] (256 KiB)
  char* ws = (char*)d_ws;
  _Float16* U = (_Float16*)ws;
  unsigned long long* hbuf =
      (unsigned long long*)(ws + (size_t)SEQ * NB * HID * 2);

  // parity-0 buffer = h_0 = 0 with tag 0 (ws is re-poisoned 0xAA each call;
  // 0xAAAAAAAA can never equal a tag in [0,1024], so parity-1 needs no init)
  (void)hipMemsetAsync(hbuf, 0, (size_t)NB * 256 * 8, stream);

  rnn_prepass<<<dim3(4, 512), dim3(256), 0, stream>>>(X, W, bias, U);

  const float* Wp = W;
  const _Float16* Up = U;
  unsigned long long* hb = hbuf;
  float* op = out;
  void* args[] = {(void*)&Wp, (void*)&Up, (void*)&hb, (void*)&op};
  // cooperative launch: all 256 spinning WGs co-resident (1 WG/CU)
  hipError_t e = hipLaunchCooperativeKernel(
      reinterpret_cast<void*>(rnn_recur), dim3(256), dim3(256), args, 0, stream);
  if (e != hipSuccess) {
    rnn_recur<<<dim3(256), dim3(256), 0, stream>>>(Wp, Up, hb, op);
  }
}